// Round 1
// baseline (451.866 us; speedup 1.0000x reference)
//
#include <hip/hip_runtime.h>

#define T_STEPS 1024
#define CC 6
#define LOG2E 1.4426950408889634f
#define LN2   0.6931471805599453f

__device__ __forceinline__ float fexp2(float x) {
#if __has_builtin(__builtin_amdgcn_exp2f)
    return __builtin_amdgcn_exp2f(x);
#else
    return exp2f(x);
#endif
}

__device__ __forceinline__ float flog2(float x) {
#if __has_builtin(__builtin_amdgcn_logf)
    return __builtin_amdgcn_logf(x);   // v_log_f32 = log2
#else
    return log2f(x);
#endif
}

// broadcast value from lane ((lane & ~7) | i) within each 8-lane group
template <int I>
__device__ __forceinline__ float group_bcast(float v) {
#if __has_builtin(__builtin_amdgcn_ds_swizzle)
    return __int_as_float(__builtin_amdgcn_ds_swizzle(__float_as_int(v), (I << 5) | 0x18));
#else
    return __shfl(v, I, 8);
#endif
}

// One 8-lane group per batch row b. Lane j (0..5) owns channel j; lanes 6,7
// shadow lane 5 (same loads, same math, same store address+value) so the wave
// never diverges.
__global__ __launch_bounds__(256, 1) void transfer_kernel(
    const float* __restrict__ feats,
    const float* __restrict__ alpha,
    const float* __restrict__ trans,
    float* __restrict__ out, int B)
{
    int tid = blockIdx.x * blockDim.x + threadIdx.x;
    int b   = tid >> 3;
    int j   = tid & 7;
    int jl  = j < CC ? j : (CC - 1);
    if (b >= B) return;

    // a = sigmoid(alpha)
    float a  = 1.0f / (1.0f + fexp2(-alpha[0] * LOG2E));
    float c1 = (1.0f - a) * LN2;   // (1-a) * ln2: converts log2-sum to natural te

    // column jl of row-softmax(trans), pre-scaled by log2e
    float tcol[CC];
#pragma unroll
    for (int i = 0; i < CC; ++i) {
        float rs = 0.0f;
#pragma unroll
        for (int k = 0; k < CC; ++k)
            rs += fexp2(trans[i * CC + k] * LOG2E);
        tcol[i] = (fexp2(trans[i * CC + jl] * LOG2E) / rs) * LOG2E;
    }

    const float* fb = feats + (size_t)b * T_STEPS * CC;
    float*       ob = out   + (size_t)b * T_STEPS * CC;

    // t = 0: state = feats[:,0], emitted as-is
    float state = fb[jl];
    ob[jl] = state;

    float x_next = fb[CC + jl];

#pragma unroll 4
    for (int t = 1; t < T_STEPS - 1; ++t) {
        float x = x_next;
        x_next = fb[(t + 1) * CC + jl];   // prefetch next step

        float sum = 0.0f;
        sum += fexp2(group_bcast<0>(state) * tcol[0]);
        sum += fexp2(group_bcast<1>(state) * tcol[1]);
        sum += fexp2(group_bcast<2>(state) * tcol[2]);
        sum += fexp2(group_bcast<3>(state) * tcol[3]);
        sum += fexp2(group_bcast<4>(state) * tcol[4]);
        sum += fexp2(group_bcast<5>(state) * tcol[5]);

        state = a * x + c1 * flog2(sum);
        ob[t * CC + jl] = state;
    }

    // final step (no prefetch)
    {
        float x = x_next;
        float sum = 0.0f;
        sum += fexp2(group_bcast<0>(state) * tcol[0]);
        sum += fexp2(group_bcast<1>(state) * tcol[1]);
        sum += fexp2(group_bcast<2>(state) * tcol[2]);
        sum += fexp2(group_bcast<3>(state) * tcol[3]);
        sum += fexp2(group_bcast<4>(state) * tcol[4]);
        sum += fexp2(group_bcast<5>(state) * tcol[5]);
        state = a * x + c1 * flog2(sum);
        ob[(T_STEPS - 1) * CC + jl] = state;
    }
}

extern "C" void kernel_launch(void* const* d_in, const int* in_sizes, int n_in,
                              void* d_out, int out_size, void* d_ws, size_t ws_size,
                              hipStream_t stream) {
    const float* feats = (const float*)d_in[0];
    const float* alpha = (const float*)d_in[1];
    const float* trans = (const float*)d_in[2];
    float* out = (float*)d_out;

    int B = in_sizes[0] / (T_STEPS * CC);   // 8192
    int threads = B * 8;                    // 8 lanes per batch row
    int block = 256;
    int grid = (threads + block - 1) / block;

    hipLaunchKernelGGL(transfer_kernel, dim3(grid), dim3(block), 0, stream,
                       feats, alpha, trans, out, B);
}